// Round 8
// baseline (2576.328 us; speedup 1.0000x reference)
//
#include <hip/hip_runtime.h>
#include <hip/hip_bf16.h>
#include <cstdint>
#include <cstring>

#define NN 100000
#define NE 1600000
#define HID 64
#define EPS 1e-5f

typedef __bf16 bf16_t;
typedef __attribute__((ext_vector_type(8))) __bf16 bf16x8;
typedef __attribute__((ext_vector_type(4))) float f32x4;
typedef __attribute__((ext_vector_type(2))) float f32x2;

#define LDS_FENCE() asm volatile("s_waitcnt lgkmcnt(0)" ::: "memory")

// ---------------- dtype detectors ----------------
__global__ void k_detect(const unsigned* __restrict__ xw, const int* __restrict__ eiw,
                         int* __restrict__ flags) {
  int lane = threadIdx.x;  // 64
  unsigned u = xw[lane];
  unsigned lo = u & 0xFFFFu;
  unsigned e = (lo >> 7) & 0xFFu;
  bool bf_ok = (lo == 0u) || (e >= 0x50u && e <= 0x8Fu);
  unsigned long long b1 = __ballot(bf_ok);
  int v = eiw[2 * lane + 1];
  unsigned long long b2 = __ballot(v == 0);
  if (lane == 0) {
    flags[0] = (b1 == ~0ull) ? 1 : 0;
    flags[1] = (b2 == ~0ull) ? 1 : 0;
  }
}

// ---------------- input canonicalization ----------------
struct FPtrs {
  const void* p[17];
  int len[17];
  int ofs[17];
};

template <typename FT>
__global__ void k_cvt_f(FPtrs fp, float* __restrict__ canon, const int* __restrict__ flags,
                        int total) {
  if (flags[0] != (int)(sizeof(FT) == 2)) return;
  int i = blockIdx.x * blockDim.x + threadIdx.x;
  int stride = gridDim.x * blockDim.x;
  for (int t = i; t < total; t += stride) {
    int seg = 0;
    while (seg < 16 && t >= fp.ofs[seg] + fp.len[seg]) ++seg;
    canon[t] = (float)((const FT*)fp.p[seg])[t - fp.ofs[seg]];
  }
}

template <typename IT>
__global__ void k_cvt_idx(const IT* __restrict__ ei, int* __restrict__ eic,
                          const int* __restrict__ flags) {
  if (flags[1] != (int)(sizeof(IT) == 8)) return;
  int i = blockIdx.x * blockDim.x + threadIdx.x;
  int stride = gridDim.x * blockDim.x;
  for (int t = i; t < 2 * NE; t += stride) eic[t] = (int)ei[t];
}

// ---------------- utility: zero fill ----------------
__global__ void k_zero4(f32x4* __restrict__ p, int n4) {
  int i = blockIdx.x * blockDim.x + threadIdx.x;
  int stride = gridDim.x * blockDim.x;
  f32x4 z = {0.f, 0.f, 0.f, 0.f};
  for (int t = i; t < n4; t += stride) p[t] = z;
}

// ---------------- CSR build (dst-major, for GCN gather) ----------------
__global__ void k_count(const int* __restrict__ col, int* __restrict__ cnt) {
  int i = blockIdx.x * blockDim.x + threadIdx.x;
  int stride = gridDim.x * blockDim.x;
  for (int e = i; e < NE; e += stride) atomicAdd(&cnt[col[e]], 1);
}

__global__ void k_dinv(const int* __restrict__ cnt, float* __restrict__ d) {
  int n = blockIdx.x * blockDim.x + threadIdx.x;
  if (n < NN) d[n] = rsqrtf((float)cnt[n] + 1.0f);  // self-loop
}

__global__ void k_scan1(const int* __restrict__ cnt, int* __restrict__ rowptr,
                        int* __restrict__ bsum, int nvals) {
  __shared__ int tmp[256];
  int gid = blockIdx.x * 256 + threadIdx.x;
  int v = (gid < nvals) ? cnt[gid] : 0;
  tmp[threadIdx.x] = v;
  __syncthreads();
  for (int s = 1; s < 256; s <<= 1) {
    int add = (threadIdx.x >= s) ? tmp[threadIdx.x - s] : 0;
    __syncthreads();
    tmp[threadIdx.x] += add;
    __syncthreads();
  }
  if (gid < nvals) rowptr[gid] = tmp[threadIdx.x] - v;
  if (threadIdx.x == 255) bsum[blockIdx.x] = tmp[255];
}

__global__ void k_scan2(int* __restrict__ bsum, int* __restrict__ btop, int nblocks) {
  __shared__ int tmp[512];
  int v = (threadIdx.x < nblocks) ? bsum[threadIdx.x] : 0;
  tmp[threadIdx.x] = v;
  __syncthreads();
  for (int s = 1; s < 512; s <<= 1) {
    int add = (threadIdx.x >= s) ? tmp[threadIdx.x - s] : 0;
    __syncthreads();
    tmp[threadIdx.x] += add;
    __syncthreads();
  }
  if (threadIdx.x < nblocks) btop[threadIdx.x] = tmp[threadIdx.x] - v;
}

__global__ void k_scan3(int* __restrict__ rowptr, const int* __restrict__ btop,
                        int* __restrict__ cursor, int nvals) {
  int gid = blockIdx.x * 256 + threadIdx.x;
  if (gid < nvals) {
    int v = rowptr[gid] + btop[blockIdx.x];
    rowptr[gid] = v;
    cursor[gid] = v;
  }
}

__global__ void k_fill(const int* __restrict__ eic, int* __restrict__ cursor,
                       int* __restrict__ csr_src) {
  int i = blockIdx.x * blockDim.x + threadIdx.x;
  int stride = gridDim.x * blockDim.x;
  for (int e = i; e < NE; e += stride) {
    int src = eic[e], dst = eic[NE + e];
    int pos = atomicAdd(&cursor[dst], 1);
    csr_src[pos] = src;
  }
}

// ---------------- layer 1: hs = (x @ W1) * dinv ----------------
__global__ void k_xw1(const float* __restrict__ x, const float* __restrict__ W1,
                      const float* __restrict__ dinv, float* __restrict__ hs) {
  int gid = blockIdx.x * blockDim.x + threadIdx.x;
  if (gid >= NN * HID) return;
  int n = gid >> 6, j = gid & 63;
  float acc = x[n * 3 + 0] * W1[0 * 64 + j] + x[n * 3 + 1] * W1[1 * 64 + j] +
              x[n * 3 + 2] * W1[2 * 64 + j];
  hs[gid] = acc * dinv[n];
}

// ---------------- hs = (h @ W) * dinv ----------------
__global__ __launch_bounds__(256) void k_hw(const float* __restrict__ h,
                                            const float* __restrict__ W,
                                            const float* __restrict__ dinv,
                                            float* __restrict__ hs) {
  __shared__ float Wl[64 * 64];
  __shared__ float hrow[4][64];
  int tid = threadIdx.x;
  for (int i = tid; i < 64 * 64; i += 256) Wl[i] = W[i];
  __syncthreads();
  int w = tid >> 6, j = tid & 63;
  for (int nb = blockIdx.x * 4 + w; nb < NN; nb += gridDim.x * 4) {
    hrow[w][j] = h[nb * 64 + j];
    LDS_FENCE();
    float acc = 0.f;
#pragma unroll 8
    for (int k = 0; k < 64; ++k) acc += hrow[w][k] * Wl[k * 64 + j];
    hs[nb * 64 + j] = acc * dinv[nb];
  }
}

// ---------------- gather-aggregate + fused finalize ----------------
template <bool RELU>
__global__ __launch_bounds__(256) void k_gather(const int* __restrict__ rowptr,
                                                const int* __restrict__ cnt,
                                                const int* __restrict__ csr_src,
                                                const float* __restrict__ hs,
                                                const float* __restrict__ dinv,
                                                const float* __restrict__ b,
                                                float* __restrict__ outf) {
  int wid = (blockIdx.x * blockDim.x + threadIdx.x) >> 6;
  int nw = (gridDim.x * blockDim.x) >> 6;
  int j = threadIdx.x & 63;
  for (int n = wid; n < NN; n += nw) {
    int beg = rowptr[n], c = cnt[n];
    float acc = hs[n * 64 + j];  // self-loop
    int k = 0;
    for (; k + 8 <= c; k += 8) {
      int s0 = csr_src[beg + k + 0], s1 = csr_src[beg + k + 1];
      int s2 = csr_src[beg + k + 2], s3 = csr_src[beg + k + 3];
      int s4 = csr_src[beg + k + 4], s5 = csr_src[beg + k + 5];
      int s6 = csr_src[beg + k + 6], s7 = csr_src[beg + k + 7];
      float v0 = hs[s0 * 64 + j], v1 = hs[s1 * 64 + j];
      float v2 = hs[s2 * 64 + j], v3 = hs[s3 * 64 + j];
      float v4 = hs[s4 * 64 + j], v5 = hs[s5 * 64 + j];
      float v6 = hs[s6 * 64 + j], v7 = hs[s7 * 64 + j];
      acc += ((v0 + v1) + (v2 + v3)) + ((v4 + v5) + (v6 + v7));
    }
    for (; k < c; ++k) acc += hs[csr_src[beg + k] * 64 + j];
    float v = acc * dinv[n] + b[j];
    outf[n * 64 + j] = RELU ? fmaxf(v, 0.f) : v;
  }
}

// ---------------- node-level factorization: u = h3@Wm1_top, v = h3@Wm1_bot ----------------
__global__ __launch_bounds__(256) void k_uv(const float* __restrict__ h3,
                                            const float* __restrict__ Wm1f,
                                            bf16_t* __restrict__ u, bf16_t* __restrict__ v) {
  __shared__ float Wt[64 * 64];
  __shared__ float Wb[64 * 64];
  __shared__ float hrow[4][64];
  int tid = threadIdx.x;
  for (int i = tid; i < 64 * 64; i += 256) {
    Wt[i] = Wm1f[i];
    Wb[i] = Wm1f[4096 + i];
  }
  __syncthreads();
  int w = tid >> 6, j = tid & 63;
  for (int nb = blockIdx.x * 4 + w; nb < NN; nb += gridDim.x * 4) {
    hrow[w][j] = h3[nb * 64 + j];
    LDS_FENCE();
    float au = 0.f, av = 0.f;
#pragma unroll 8
    for (int k = 0; k < 64; ++k) {
      float hv = hrow[w][k];
      au += hv * Wt[k * 64 + j];
      av += hv * Wb[k * 64 + j];
    }
    u[nb * 64 + j] = (bf16_t)au;
    v[nb * 64 + j] = (bf16_t)av;
  }
}

// ---------------- edge-pass helpers ----------------
// per-lane a1 slice (A-layout): edge e = t*16+n, k = q*8+j (j<8) and 32+q*8+j (j>=8)
__device__ __forceinline__ void load_a1(const int* __restrict__ eic,
                                        const bf16_t* __restrict__ u,
                                        const bf16_t* __restrict__ v,
                                        const float bk[16], int t, int n, int q,
                                        float a1k[16]) {
  int e = t * 16 + n;
  int src = eic[e], dst = eic[NE + e];
  const bf16x8* pu = (const bf16x8*)(u + src * 64);
  const bf16x8* pv = (const bf16x8*)(v + dst * 64);
  bf16x8 ua = pu[q], ub = pu[4 + q], va = pv[q], vb = pv[4 + q];
#pragma unroll
  for (int j = 0; j < 8; ++j) {
    a1k[j] = fmaxf((float)ua[j] + (float)va[j] + bk[j], 0.f);
    a1k[8 + j] = fmaxf((float)ub[j] + (float)vb[j] + bk[8 + j], 0.f);
  }
}

__device__ __forceinline__ void load_b2(const float* __restrict__ Wm2f, int n, int q,
                                        bf16x8 b2h[2][2], const float* __restrict__ bm2f,
                                        float bias2[2]) {
#pragma unroll
  for (int ks = 0; ks < 2; ++ks)
#pragma unroll
    for (int ct = 0; ct < 2; ++ct)
#pragma unroll
      for (int j = 0; j < 8; ++j)
        b2h[ks][ct][j] = (bf16_t)Wm2f[(ks * 32 + q * 8 + j) * 32 + ct * 16 + n];
#pragma unroll
  for (int ct = 0; ct < 2; ++ct) bias2[ct] = bm2f[ct * 16 + n];
}

// z1_bn = s1*a1+t1 (f32), hi/lo split -> a2 = relu(z1_bn @ Wm2 + bm2) (C-layout)
__device__ __forceinline__ void compute_a2(const float a1k[16], const float s1k[16],
                                           const float t1k[16], const bf16x8 b2h[2][2],
                                           const float bias2[2], f32x4 a2c[2]) {
  bf16x8 g0h, g0l, g1h, g1l;
#pragma unroll
  for (int j = 0; j < 8; ++j) {
    float z0 = a1k[j] * s1k[j] + t1k[j];
    float z1 = a1k[8 + j] * s1k[8 + j] + t1k[8 + j];
    bf16_t h0 = (bf16_t)z0, h1 = (bf16_t)z1;
    g0h[j] = h0; g0l[j] = (bf16_t)(z0 - (float)h0);
    g1h[j] = h1; g1l[j] = (bf16_t)(z1 - (float)h1);
  }
#pragma unroll
  for (int ct = 0; ct < 2; ++ct) {
    f32x4 c = {0.f, 0.f, 0.f, 0.f};
    c = __builtin_amdgcn_mfma_f32_16x16x32_bf16(g0h, b2h[0][ct], c, 0, 0, 0);
    c = __builtin_amdgcn_mfma_f32_16x16x32_bf16(g0l, b2h[0][ct], c, 0, 0, 0);
    c = __builtin_amdgcn_mfma_f32_16x16x32_bf16(g1h, b2h[1][ct], c, 0, 0, 0);
    c = __builtin_amdgcn_mfma_f32_16x16x32_bf16(g1l, b2h[1][ct], c, 0, 0, 0);
#pragma unroll
    for (int r = 0; r < 4; ++r) a2c[ct][r] = fmaxf(c[r] + bias2[ct], 0.f);
  }
}

// ============ pass 1: BN1 stats of a1 = relu(u[src]+v[dst]+bm1) ============
__global__ __launch_bounds__(256) void k_e1(const int* __restrict__ eic,
                                            const bf16_t* __restrict__ u,
                                            const bf16_t* __restrict__ v,
                                            const float* __restrict__ bm1f,
                                            float* __restrict__ sum1,
                                            float* __restrict__ sq1) {
  int lane = threadIdx.x & 63;
  int wave = blockIdx.x * 4 + (threadIdx.x >> 6);
  int nwaves = gridDim.x * 4;
  int n = lane & 15, q = lane >> 4;
  float bk[16];
#pragma unroll
  for (int j = 0; j < 8; ++j) {
    bk[j] = bm1f[q * 8 + j];
    bk[8 + j] = bm1f[32 + q * 8 + j];
  }
  float accs[16], accq[16];
#pragma unroll
  for (int j = 0; j < 16; ++j) { accs[j] = 0.f; accq[j] = 0.f; }
  for (int t = wave; t < NE / 16; t += nwaves) {
    float a1k[16];
    load_a1(eic, u, v, bk, t, n, q, a1k);
#pragma unroll
    for (int j = 0; j < 16; ++j) {
      accs[j] += a1k[j];
      accq[j] += a1k[j] * a1k[j];
    }
  }
  // reduce over n (lane bits 0-3)
#pragma unroll
  for (int j = 0; j < 16; ++j) {
    float s = accs[j], qq = accq[j];
    s += __shfl_xor(s, 1); s += __shfl_xor(s, 2);
    s += __shfl_xor(s, 4); s += __shfl_xor(s, 8);
    qq += __shfl_xor(qq, 1); qq += __shfl_xor(qq, 2);
    qq += __shfl_xor(qq, 4); qq += __shfl_xor(qq, 8);
    if (n == 0) {
      int col = (j < 8) ? (q * 8 + j) : (32 + q * 8 + (j - 8));
      unsafeAtomicAdd(&sum1[col], s);
      unsafeAtomicAdd(&sq1[col], qq);
    }
  }
}

// ---------------- BN affine constants ----------------
__global__ void k_bnconst(const float* __restrict__ sum, const float* __restrict__ sq,
                          const float* __restrict__ g, const float* __restrict__ be,
                          float* __restrict__ sarr, float* __restrict__ tarr, int ncol) {
  int j = threadIdx.x;
  if (j >= ncol) return;
  float mu = sum[j] / (float)NE;
  float var = fmaxf(sq[j] / (float)NE - mu * mu, 0.f);
  float s = g[j] * rsqrtf(var + EPS);
  sarr[j] = s;
  tarr[j] = be[j] - mu * s;
}

// ============ pass 2: BN2 stats of a2 (+ optional store of pre-BN a2) ============
template <bool STORE>
__global__ __launch_bounds__(256) void k_e2(const int* __restrict__ eic,
                                            const bf16_t* __restrict__ u,
                                            const bf16_t* __restrict__ v,
                                            const float* __restrict__ bm1f,
                                            const float* __restrict__ s1, const float* __restrict__ t1,
                                            const float* __restrict__ Wm2f,
                                            const float* __restrict__ bm2f,
                                            bf16_t* __restrict__ a2s,
                                            float* __restrict__ sum2,
                                            float* __restrict__ sq2) {
  int lane = threadIdx.x & 63;
  int wave = blockIdx.x * 4 + (threadIdx.x >> 6);
  int nwaves = gridDim.x * 4;
  int n = lane & 15, q = lane >> 4;
  float bk[16], s1k[16], t1k[16];
#pragma unroll
  for (int j = 0; j < 8; ++j) {
    bk[j] = bm1f[q * 8 + j];       bk[8 + j] = bm1f[32 + q * 8 + j];
    s1k[j] = s1[q * 8 + j];        s1k[8 + j] = s1[32 + q * 8 + j];
    t1k[j] = t1[q * 8 + j];        t1k[8 + j] = t1[32 + q * 8 + j];
  }
  bf16x8 b2h[2][2];
  float bias2[2];
  load_b2(Wm2f, n, q, b2h, bm2f, bias2);
  float accs[2] = {0, 0}, accq[2] = {0, 0};
  for (int t = wave; t < NE / 16; t += nwaves) {
    float a1k[16];
    load_a1(eic, u, v, bk, t, n, q, a1k);
    f32x4 a2c[2];
    compute_a2(a1k, s1k, t1k, b2h, bias2, a2c);
#pragma unroll
    for (int ct = 0; ct < 2; ++ct)
#pragma unroll
      for (int r = 0; r < 4; ++r) {
        float vv = a2c[ct][r];
        if (STORE) a2s[(size_t)(t * 16 + q * 4 + r) * 32 + ct * 16 + n] = (bf16_t)vv;
        accs[ct] += vv;
        accq[ct] += vv * vv;
      }
  }
#pragma unroll
  for (int ct = 0; ct < 2; ++ct) {
    float s = accs[ct], qq = accq[ct];
    s += __shfl_xor(s, 16); s += __shfl_xor(s, 32);
    qq += __shfl_xor(qq, 16); qq += __shfl_xor(qq, 32);
    if (lane < 16) {
      unsafeAtomicAdd(&sum2[ct * 16 + lane], s);
      unsafeAtomicAdd(&sq2[ct * 16 + lane], qq);
    }
  }
}

// ============ pass 3 tier B: stream stored a2 (original order) -> out ============
template <typename OT>
__global__ __launch_bounds__(256) void k_out_stream(const bf16_t* __restrict__ a2s,
                                                    const float* __restrict__ s2,
                                                    const float* __restrict__ t2,
                                                    const float* __restrict__ Wm3f,
                                                    const float* __restrict__ bm3f,
                                                    OT* __restrict__ out,
                                                    const int* __restrict__ flags) {
  if (flags[0] != (int)(sizeof(OT) == 2)) return;
  int lane = threadIdx.x & 63;
  int wave = blockIdx.x * 4 + (threadIdx.x >> 6);
  int nwaves = gridDim.x * 4;
  int half = lane & 1;
  int sub = lane >> 1;  // 0..31
  float s2c[16], t2c[16], w0[16], w1[16];
#pragma unroll
  for (int i = 0; i < 16; ++i) {
    int c = half * 16 + i;
    s2c[i] = s2[c]; t2c[i] = t2[c];
    w0[i] = Wm3f[c * 2 + 0]; w1[i] = Wm3f[c * 2 + 1];
  }
  float bb0 = bm3f[0], bb1 = bm3f[1];
  const int ntiles = NE / 32;
  for (int t = wave; t < ntiles; t += nwaves) {
    int e = t * 32 + sub;
    const bf16x8* pa = (const bf16x8*)(a2s + (size_t)e * 32 + half * 16);
    bf16x8 v0 = pa[0], v1 = pa[1];
    float o0 = 0.f, o1 = 0.f;
#pragma unroll
    for (int i = 0; i < 8; ++i) {
      float z = (float)v0[i] * s2c[i] + t2c[i];
      o0 += z * w0[i]; o1 += z * w1[i];
      float z2 = (float)v1[i] * s2c[8 + i] + t2c[8 + i];
      o0 += z2 * w0[8 + i]; o1 += z2 * w1[8 + i];
    }
    o0 += __shfl_xor(o0, 1);
    o1 += __shfl_xor(o1, 1);
    if (half == 0) {
      o0 += bb0; o1 += bb1;
      if (sizeof(OT) == 2) {
        bf16_t p[2] = {(bf16_t)o0, (bf16_t)o1};
        unsigned pw;
        memcpy(&pw, p, 4);
        ((unsigned*)out)[e] = pw;
      } else {
        f32x2 pw = {o0, o1};
        ((f32x2*)out)[e] = pw;
      }
    }
  }
}

// ============ pass 3 tier C: recompute a2 and reduce -> out ============
template <typename OT>
__global__ __launch_bounds__(256) void k_out_recomp(const int* __restrict__ eic,
                                                    const bf16_t* __restrict__ u,
                                                    const bf16_t* __restrict__ v,
                                                    const float* __restrict__ bm1f,
                                                    const float* __restrict__ s1, const float* __restrict__ t1,
                                                    const float* __restrict__ Wm2f,
                                                    const float* __restrict__ bm2f,
                                                    const float* __restrict__ s2, const float* __restrict__ t2,
                                                    const float* __restrict__ Wm3f,
                                                    const float* __restrict__ bm3f,
                                                    OT* __restrict__ out,
                                                    const int* __restrict__ flags) {
  if (flags[0] != (int)(sizeof(OT) == 2)) return;
  int lane = threadIdx.x & 63;
  int wave = blockIdx.x * 4 + (threadIdx.x >> 6);
  int nwaves = gridDim.x * 4;
  int n = lane & 15, q = lane >> 4;
  float bk[16], s1k[16], t1k[16];
#pragma unroll
  for (int j = 0; j < 8; ++j) {
    bk[j] = bm1f[q * 8 + j];       bk[8 + j] = bm1f[32 + q * 8 + j];
    s1k[j] = s1[q * 8 + j];        s1k[8 + j] = s1[32 + q * 8 + j];
    t1k[j] = t1[q * 8 + j];        t1k[8 + j] = t1[32 + q * 8 + j];
  }
  bf16x8 b2h[2][2];
  float bias2[2];
  load_b2(Wm2f, n, q, b2h, bm2f, bias2);
  float s2c[2], t2c[2];
#pragma unroll
  for (int ct = 0; ct < 2; ++ct) { s2c[ct] = s2[ct * 16 + n]; t2c[ct] = t2[ct * 16 + n]; }
  float w3a0 = Wm3f[n * 2 + 0], w3a1 = Wm3f[n * 2 + 1];
  float w3b0 = Wm3f[(16 + n) * 2 + 0], w3b1 = Wm3f[(16 + n) * 2 + 1];
  float bb0 = bm3f[0], bb1 = bm3f[1];

  for (int t = wave; t < NE / 16; t += nwaves) {
    float a1k[16];
    load_a1(eic, u, v, bk, t, n, q, a1k);
    f32x4 a2c[2];
    compute_a2(a1k, s1k, t1k, b2h, bias2, a2c);
#pragma unroll
    for (int r = 0; r < 4; ++r) {
      float z0 = a2c[0][r] * s2c[0] + t2c[0];
      float z1 = a2c[1][r] * s2c[1] + t2c[1];
      float o0 = z0 * w3a0 + z1 * w3b0;
      float o1 = z0 * w3a1 + z1 * w3b1;
      o0 += __shfl_xor(o0, 1); o0 += __shfl_xor(o0, 2);
      o0 += __shfl_xor(o0, 4); o0 += __shfl_xor(o0, 8);
      o1 += __shfl_xor(o1, 1); o1 += __shfl_xor(o1, 2);
      o1 += __shfl_xor(o1, 4); o1 += __shfl_xor(o1, 8);
      if (n == 0) {
        int e = t * 16 + q * 4 + r;
        o0 += bb0; o1 += bb1;
        if (sizeof(OT) == 2) {
          bf16_t p[2] = {(bf16_t)o0, (bf16_t)o1};
          unsigned pw;
          memcpy(&pw, p, 4);
          ((unsigned*)out)[e] = pw;
        } else {
          f32x2 pw = {o0, o1};
          ((f32x2*)out)[e] = pw;
        }
      }
    }
  }
}

// ---------------- host ----------------
extern "C" void kernel_launch(void* const* d_in, const int* in_sizes, int n_in,
                              void* d_out, int out_size, void* d_ws, size_t ws_size,
                              hipStream_t stream) {
  (void)n_in; (void)in_sizes; (void)out_size;

  char* ws = (char*)d_ws;
  size_t off = 0;
  auto alloc = [&](size_t bytes) {
    size_t r = off;
    off = (off + bytes + 255) & ~(size_t)255;
    return r;
  };
  float* dinv  = (float*)(ws + alloc((size_t)NN * 4));
  float* hs    = (float*)(ws + alloc((size_t)NN * HID * 4));
  float* agg   = (float*)(ws + alloc((size_t)NN * HID * 4));
  int*   eic   = (int*)(ws + alloc((size_t)2 * NE * 4));
  float* stats = (float*)(ws + alloc(192 * 4));
  float* sum1 = stats, *sq1 = stats + 64, *sum2 = stats + 128, *sq2 = stats + 160;
  int*   flags = (int*)(ws + alloc(256));
  float* s1arr = (float*)(ws + alloc(64 * 4));
  float* t1arr = (float*)(ws + alloc(64 * 4));
  float* s2arr = (float*)(ws + alloc(32 * 4));
  float* t2arr = (float*)(ws + alloc(32 * 4));
  // dst-CSR (GCN gather)
  int* cnt     = (int*)(ws + alloc((size_t)NN * 4));
  int* rowptr  = (int*)(ws + alloc((size_t)NN * 4));
  int* cursor  = (int*)(ws + alloc((size_t)NN * 4));
  int* bsum    = (int*)(ws + alloc(512 * 4));
  int* btop    = (int*)(ws + alloc(512 * 4));
  int* csr_src = (int*)(ws + alloc((size_t)NE * 4));
  // node-level MLP factors
  bf16_t* u    = (bf16_t*)(ws + alloc((size_t)NN * HID * 2));
  bf16_t* v    = (bf16_t*)(ws + alloc((size_t)NN * HID * 2));

  // canonical f32 input block
  static const int flens[17] = {NN * 3, 3 * 64, 64, 64 * 64, 64, 64 * 64, 64,
                                128 * 64, 64, 64, 64, 64 * 32, 32, 32, 32, 32 * 2, 2};
  FPtrs fp;
  int total_f = 0;
  {
    int fi = 0;
    for (int i = 0; i < 18; ++i) {
      if (i == 1) continue;
      fp.p[fi] = d_in[i];
      fp.len[fi] = flens[fi];
      fp.ofs[fi] = total_f;
      total_f += flens[fi];
      ++fi;
    }
  }
  float* canon = (float*)(ws + alloc((size_t)total_f * 4));
  size_t a2_off = alloc((size_t)NE * 32 * 2);
  bf16_t* a2s = (bf16_t*)(ws + a2_off);
  bool tierB = (a2_off + (size_t)NE * 32 * 2) <= ws_size;

  const float* xf   = canon + fp.ofs[0];
  const float* W1f  = canon + fp.ofs[1];
  const float* b1f  = canon + fp.ofs[2];
  const float* W2f  = canon + fp.ofs[3];
  const float* b2f  = canon + fp.ofs[4];
  const float* W3f  = canon + fp.ofs[5];
  const float* b3f  = canon + fp.ofs[6];
  const float* Wm1f = canon + fp.ofs[7];
  const float* bm1f = canon + fp.ofs[8];
  const float* g1f  = canon + fp.ofs[9];
  const float* be1f = canon + fp.ofs[10];
  const float* Wm2f = canon + fp.ofs[11];
  const float* bm2f = canon + fp.ofs[12];
  const float* g2f  = canon + fp.ofs[13];
  const float* be2f = canon + fp.ofs[14];
  const float* Wm3f = canon + fp.ofs[15];
  const float* bm3f = canon + fp.ofs[16];

  const int nh = NN * HID;
  const int nscanb = (NN + 255) / 256;  // 391

  // 0) detect dtypes, canonicalize
  k_detect<<<1, 64, 0, stream>>>((const unsigned*)d_in[0], (const int*)d_in[1], flags);
  k_cvt_idx<int><<<1600, 256, 0, stream>>>((const int*)d_in[1], eic, flags);
  k_cvt_idx<long long><<<1600, 256, 0, stream>>>((const long long*)d_in[1], eic, flags);
  k_cvt_f<float><<<640, 256, 0, stream>>>(fp, canon, flags, total_f);
  k_cvt_f<bf16_t><<<640, 256, 0, stream>>>(fp, canon, flags, total_f);

  // 1) CSR build + dinv + stats zero
  k_zero4<<<128, 256, 0, stream>>>((f32x4*)cnt, NN / 4);
  k_zero4<<<1, 64, 0, stream>>>((f32x4*)stats, 48);
  k_count<<<1600, 256, 0, stream>>>(eic + NE, cnt);
  k_dinv<<<(NN + 255) / 256, 256, 0, stream>>>(cnt, dinv);
  k_scan1<<<nscanb, 256, 0, stream>>>(cnt, rowptr, bsum, NN);
  k_scan2<<<1, 512, 0, stream>>>(bsum, btop, nscanb);
  k_scan3<<<nscanb, 256, 0, stream>>>(rowptr, btop, cursor, NN);
  k_fill<<<1600, 256, 0, stream>>>(eic, cursor, csr_src);

  // ---- GCN layer 1 ----
  k_xw1<<<(nh + 255) / 256, 256, 0, stream>>>(xf, W1f, dinv, hs);
  k_gather<true><<<2048, 256, 0, stream>>>(rowptr, cnt, csr_src, hs, dinv, b1f, agg);

  // ---- GCN layer 2 ----
  k_hw<<<4096, 256, 0, stream>>>(agg, W2f, dinv, hs);
  k_gather<true><<<2048, 256, 0, stream>>>(rowptr, cnt, csr_src, hs, dinv, b2f, agg);

  // ---- GCN layer 3 (h3 in f32, no relu) ----
  k_hw<<<4096, 256, 0, stream>>>(agg, W3f, dinv, hs);
  k_gather<false><<<2048, 256, 0, stream>>>(rowptr, cnt, csr_src, hs, dinv, b3f, agg);

  // ---- node-level factorization of MLP layer 1 ----
  k_uv<<<4096, 256, 0, stream>>>(agg, Wm1f, u, v);

  // ---- edge MLP ----
  k_e1<<<2048, 256, 0, stream>>>(eic, u, v, bm1f, sum1, sq1);
  k_bnconst<<<1, 64, 0, stream>>>(sum1, sq1, g1f, be1f, s1arr, t1arr, 64);
  if (tierB) {
    k_e2<true><<<2048, 256, 0, stream>>>(eic, u, v, bm1f, s1arr, t1arr, Wm2f, bm2f, a2s,
                                         sum2, sq2);
    k_bnconst<<<1, 64, 0, stream>>>(sum2, sq2, g2f, be2f, s2arr, t2arr, 32);
    k_out_stream<float><<<2048, 256, 0, stream>>>(a2s, s2arr, t2arr, Wm3f, bm3f,
                                                  (float*)d_out, flags);
    k_out_stream<bf16_t><<<2048, 256, 0, stream>>>(a2s, s2arr, t2arr, Wm3f, bm3f,
                                                   (bf16_t*)d_out, flags);
  } else {
    k_e2<false><<<2048, 256, 0, stream>>>(eic, u, v, bm1f, s1arr, t1arr, Wm2f, bm2f, a2s,
                                          sum2, sq2);
    k_bnconst<<<1, 64, 0, stream>>>(sum2, sq2, g2f, be2f, s2arr, t2arr, 32);
    k_out_recomp<float><<<2048, 256, 0, stream>>>(eic, u, v, bm1f, s1arr, t1arr, Wm2f,
                                                  bm2f, s2arr, t2arr, Wm3f, bm3f,
                                                  (float*)d_out, flags);
    k_out_recomp<bf16_t><<<2048, 256, 0, stream>>>(eic, u, v, bm1f, s1arr, t1arr, Wm2f,
                                                   bm2f, s2arr, t2arr, Wm3f, bm3f,
                                                   (bf16_t*)d_out, flags);
  }
}